// Round 13
// baseline (4287.218 us; speedup 1.0000x reference)
//
#include <hip/hip_runtime.h>
#include <hip/hip_fp16.h>
#include <math.h>

// DirModelToFace on MI355X — round 13:
//  * FIX round-12 regression: fp16 y in [b][r4][32] made each per-batch store
//    segment 64B = half-line -> RMW fetch (FETCH 112->119MB, dur 124->130us).
//    msg now stored fp16 in INTERLEAVED [4*vert+q][b][32] layout (same as vH/fH):
//    per row the wave stores 256B contiguous = 2 full lines, no RMW, NT intact.
//    gemm mode-0 B-read: msgH[(4*vert+(kk>>5))*128 + b*32 + (kk&31)], b/vert
//    precomputed per row-group outside the K-loop.
//  * rest as round 12: BK=64 gemm (40KB LDS, 8 barriers), NT edge loads, fused
//    producer BN stats + avgpool, truncation A-split, layer-0 spmm skip, dead
//    layer 15 removed, CSR build with packed edges.

#define EPS 1e-5f

typedef float floatx4 __attribute__((ext_vector_type(4)));
typedef short shortx8 __attribute__((ext_vector_type(8)));
typedef int intx2 __attribute__((ext_vector_type(2)));
typedef int intx4 __attribute__((ext_vector_type(4)));

__device__ __forceinline__ float eluf(float x) { return x > 0.f ? x : expm1f(x); }
__device__ __forceinline__ float4 elu4(float4 v) {
    v.x = eluf(v.x); v.y = eluf(v.y); v.z = eluf(v.z); v.w = eluf(v.w); return v;
}
__device__ __forceinline__ short f2bf(float x) {  // round-to-nearest-even bf16
    unsigned u = __builtin_bit_cast(unsigned, x);
    u = u + 0x7FFFu + ((u >> 16) & 1u);
    return (short)(u >> 16);
}
__device__ __forceinline__ float bf2f(short h) {
    unsigned u = ((unsigned)(unsigned short)h) << 16;
    return __builtin_bit_cast(float, u);
}
// truncation hi/lo split: rem = x-bf2f(hi) exact in fp32; total err <= 2^-16|x|
__device__ __forceinline__ void split2(float x, short& hi, short& lo) {
    unsigned u = __builtin_bit_cast(unsigned, x);
    hi = (short)(u >> 16);
    float r = x - bf2f(hi);
    lo = (short)(__builtin_bit_cast(unsigned, r) >> 16);
}
__device__ __forceinline__ float2 h2f(int bits) {
    return __half22float2(__builtin_bit_cast(__half2, bits));
}

// v = inputs @ W1 + b1; fp16 shadow; fused elu-stats (A-half of dir0 slot0).
__global__ void conv1_kernel(const float* __restrict__ in, const float* __restrict__ W1,
                             const float* __restrict__ b1, float* __restrict__ v,
                             __half* __restrict__ vH, int N, float* __restrict__ Sout) {
    int t = threadIdx.x;
    int c = t & 127, half = t >> 7;
    int r0 = blockIdx.x * 64;
    float w0 = W1[c], w1 = W1[128 + c], w2 = W1[256 + c], bb = b1[c];
    float s1 = 0.f, s2 = 0.f;
    for (int k = 0; k < 32; ++k) {
        int r = r0 + half + 2 * k;
        float x0 = in[r * 3 + 0], x1 = in[r * 3 + 1], x2 = in[r * 3 + 2];
        float val = bb + x0 * w0 + x1 * w1 + x2 * w2;
        v[(size_t)r * 128 + c] = val;
        int b = r / N, vert = r - b * N;
        vH[(size_t)(4 * vert + (c >> 5)) * 128 + b * 32 + (c & 31)] = __float2half(val);
        float e = eluf(val);
        s1 += e; s2 += e * e;
    }
    atomicAdd(&Sout[c], s1);
    atomicAdd(&Sout[256 + c], s2);
}

// masksum[b] = sum_n mask[b][n]
__global__ void masksum_kernel(const float* __restrict__ mask, float* __restrict__ msum,
                               int N) {
    int b = blockIdx.x, t = threadIdx.x;
    float s = 0.f;
    for (int n = t; n < N; n += 256) s += mask[(size_t)b * N + n];
    for (int o = 32; o > 0; o >>= 1) s += __shfl_down(s, o);
    __shared__ float sh[4];
    if ((t & 63) == 0) sh[t >> 6] = s;
    __syncthreads();
    if (t == 0) msum[b] = sh[0] + sh[1] + sh[2] + sh[3];
}

// ---------------- CSR build ----------------

__global__ void hist_kernel(const int* __restrict__ rows, int* __restrict__ counts) {
    int e = blockIdx.x * 256 + threadIdx.x;
    atomicAdd(&counts[rows[e]], 1);
}

__global__ void partial_kernel(const int* __restrict__ counts, int* __restrict__ partials,
                               int R) {
    int t = threadIdx.x;
    int base = blockIdx.x * 1024 + t * 4;
    int s = 0;
#pragma unroll
    for (int j = 0; j < 4; ++j) { int i = base + j; if (i < R) s += counts[i]; }
    __shared__ int sh[256];
    sh[t] = s; __syncthreads();
    for (int st = 128; st > 0; st >>= 1) {
        if (t < st) sh[t] += sh[t + st];
        __syncthreads();
    }
    if (t == 0) partials[blockIdx.x] = sh[0];
}

__global__ void scanp_kernel(int* __restrict__ partials, int* __restrict__ rowptr,
                             int P, int R, int total) {
    __shared__ int sh[256];
    int t = threadIdx.x;
    int v = (t < P) ? partials[t] : 0;
    sh[t] = v; __syncthreads();
    for (int st = 1; st < 256; st <<= 1) {
        int tmp = (t >= st) ? sh[t - st] : 0;
        __syncthreads();
        sh[t] += tmp;
        __syncthreads();
    }
    if (t < P) partials[t] = sh[t] - v;
    if (t == 0) rowptr[R] = total;
}

__global__ void apply_kernel(int* __restrict__ counts, const int* __restrict__ partials,
                             int* __restrict__ rowptr, int R) {
    int t = threadIdx.x;
    int base = blockIdx.x * 1024 + t * 4;
    int c[4]; int s = 0;
#pragma unroll
    for (int j = 0; j < 4; ++j) { int i = base + j; c[j] = (i < R) ? counts[i] : 0; s += c[j]; }
    __shared__ int sh[256];
    sh[t] = s; __syncthreads();
    for (int st = 1; st < 256; st <<= 1) {
        int tmp = (t >= st) ? sh[t - st] : 0;
        __syncthreads();
        sh[t] += tmp;
        __syncthreads();
    }
    int off = partials[blockIdx.x] + sh[t] - s;
#pragma unroll
    for (int j = 0; j < 4; ++j) {
        int i = base + j;
        if (i < R) { rowptr[i] = off; counts[i] = off; }
        off += c[j];
    }
}

__global__ void scatter_kernel(const int* __restrict__ rows, const int* __restrict__ cols,
                               const float* __restrict__ vals, int* __restrict__ fill,
                               int2* __restrict__ edges) {
    int e = blockIdx.x * 256 + threadIdx.x;
    int p = atomicAdd(&fill[rows[e]], 1);
    edges[p] = make_int2(cols[e], __float_as_int(vals[e]));
}

// ---- CSR spmm: 16 waves/block, 2 rows/wave, fp16 interleaved output, fused stats ----
// Output yH layout [r4][b][32]: per row the wave stores 256B contiguous (no RMW).
__global__ __launch_bounds__(1024) void spmm_csr_kernel(
    const int* __restrict__ rowptr, const int2* __restrict__ edges,
    const __half2* __restrict__ xH, __half* __restrict__ yH,
    float* __restrict__ Sout) {
    int t = threadIdx.x;
    int waveId = blockIdx.x * 16 + (t >> 6);
    int lane = t & 63;
    int b = lane >> 4, cp = lane & 15;
    const __half2* xb = xH + b * 16 + cp;
    const intx2* eg = (const intx2*)edges;
    __shared__ float red[256];
    if (t < 256) red[t] = 0.f;
    __syncthreads();
#pragma unroll
    for (int rr = 0; rr < 2; ++rr) {
        int r = waveId * 2 + rr;
        int e0 = rowptr[r], e1 = rowptr[r + 1];
        float ax = 0.f, ay = 0.f;
        int e = e0;
        for (; e + 4 <= e1; e += 4) {
            intx2 E0 = __builtin_nontemporal_load(&eg[e]);
            intx2 E1 = __builtin_nontemporal_load(&eg[e + 1]);
            intx2 E2 = __builtin_nontemporal_load(&eg[e + 2]);
            intx2 E3 = __builtin_nontemporal_load(&eg[e + 3]);
            __half2 g0 = xb[(size_t)E0.x * 64];
            __half2 g1 = xb[(size_t)E1.x * 64];
            __half2 g2 = xb[(size_t)E2.x * 64];
            __half2 g3 = xb[(size_t)E3.x * 64];
            float v0 = __int_as_float(E0.y), v1 = __int_as_float(E1.y);
            float v2 = __int_as_float(E2.y), v3 = __int_as_float(E3.y);
            float2 f0 = __half22float2(g0), f1 = __half22float2(g1);
            float2 f2 = __half22float2(g2), f3 = __half22float2(g3);
            ax += v0 * f0.x; ay += v0 * f0.y;
            ax += v1 * f1.x; ay += v1 * f1.y;
            ax += v2 * f2.x; ay += v2 * f2.y;
            ax += v3 * f3.x; ay += v3 * f3.y;
        }
        for (; e < e1; ++e) {
            intx2 E = __builtin_nontemporal_load(&eg[e]);
            __half2 g = xb[(size_t)E.x * 64];
            float v = __int_as_float(E.y);
            float2 f = __half22float2(g);
            ax += v * f.x; ay += v * f.y;
        }
        __half2 hv = __floats2half2_rn(ax, ay);
        __builtin_nontemporal_store(__builtin_bit_cast(int, hv),
                                    (int*)(yH + (size_t)r * 128 + b * 32 + cp * 2));
        // stats on the rounded values (what the gemm will consume)
        float2 fv = __half22float2(hv);
        float ea = eluf(fv.x), eb = eluf(fv.y);
        float s1a = ea, s2a = ea * ea, s1b = eb, s2b = eb * eb;
        s1a += __shfl_xor(s1a, 16); s1a += __shfl_xor(s1a, 32);
        s2a += __shfl_xor(s2a, 16); s2a += __shfl_xor(s2a, 32);
        s1b += __shfl_xor(s1b, 16); s1b += __shfl_xor(s1b, 32);
        s2b += __shfl_xor(s2b, 16); s2b += __shfl_xor(s2b, 32);
        if (lane < 16) {
            int ch = (r & 3) * 32 + cp * 2;
            atomicAdd(&red[ch], s1a);
            atomicAdd(&red[ch + 1], s1b);
            atomicAdd(&red[128 + ch], s2a);
            atomicAdd(&red[128 + ch + 1], s2b);
        }
    }
    __syncthreads();
    if (t < 128) atomicAdd(&Sout[128 + t], red[t]);
    else if (t < 256) atomicAdd(&Sout[384 + (t - 128)], red[t]);
}

// Fold BN into weights; emit bf16 hi/lo split in [col][k] layout for MFMA B-frags.
__global__ void fold_kernel(const float* __restrict__ S, const float* __restrict__ gamma,
                            const float* __restrict__ beta, const float* __restrict__ W,
                            const float* __restrict__ bvec, short* __restrict__ Wh,
                            short* __restrict__ Wl, float* __restrict__ bp, float invR) {
    __shared__ float red[256];
    int o = blockIdx.x, k = threadIdx.x;
    float mean = S[k] * invR;
    float var = S[256 + k] * invR - mean * mean;
    float s = gamma[k] / sqrtf(var + EPS);
    float w = W[(size_t)k * 128 + o];
    float wp = s * w;
    short h = f2bf(wp);
    Wh[(size_t)o * 256 + k] = h;
    Wl[(size_t)o * 256 + k] = f2bf(wp - bf2f(h));
    red[k] = (beta[k] - mean * s) * w;
    __syncthreads();
    for (int st = 128; st > 0; st >>= 1) {
        if (k < st) red[k] += red[k + st];
        __syncthreads();
    }
    if (k == 0) bp[o] = bvec[o] + red[0];
}

// MFMA GEMM (bf16 hi/lo split, fp32 acc), BK=64 LDS staging, fused stats+avg epilogue.
// modeB: 0 = per-row fp16 B (msgH, interleaved [4v+q][b][32]), 1 = broadcast fp32 avg,
//        2 = B identically zero.
__global__ __launch_bounds__(256) void gemm_mfma(
    const float* __restrict__ A, const __half* __restrict__ BsH,
    const float* __restrict__ Bsf, const short* __restrict__ Wh,
    const short* __restrict__ Wl, const float* __restrict__ bp,
    const float* __restrict__ resid, float* __restrict__ out,
    __half* __restrict__ shadow, float* __restrict__ Sout,
    const float* __restrict__ mask, float* __restrict__ avgout,
    int rowsPerBatch, int modeB, int eluB) {
    __shared__ short Bh2[2][128 * 40];
    __shared__ short Bl2[2][128 * 40];
    const int t = threadIdx.x;
    const int lane = t & 63;
    const int wave = t >> 6;
    const int rowBase = blockIdx.x * 128 + wave * 32;
    const int m = lane & 15;
    const int kq = lane >> 4;
    // per row-group batch/vert (row fixed per rg across the K-loop)
    int bRow[2], vRow[2];
#pragma unroll
    for (int rg = 0; rg < 2; ++rg) {
        int row = rowBase + rg * 16 + m;
        bRow[rg] = row / rowsPerBatch;
        vRow[rg] = row - bRow[rg] * rowsPerBatch;
    }
    floatx4 acc[2][8];
#pragma unroll
    for (int i = 0; i < 2; ++i)
#pragma unroll
        for (int j = 0; j < 8; ++j) acc[i][j] = {0.f, 0.f, 0.f, 0.f};

    const int kb2End = (modeB == 2) ? 2 : 4;
    for (int kb2 = 0; kb2 < kb2End; ++kb2) {
        __syncthreads();
#pragma unroll
        for (int s = 0; s < 2; ++s) {
            int kb = kb2 * 2 + s;
#pragma unroll
            for (int i = 0; i < 2; ++i) {
                int idx = t + 256 * i;
                int col = idx >> 2, q = idx & 3;
                shortx8 h = *(const shortx8*)&Wh[(size_t)col * 256 + kb * 32 + q * 8];
                shortx8 l = *(const shortx8*)&Wl[(size_t)col * 256 + kb * 32 + q * 8];
                *(shortx8*)&Bh2[s][col * 40 + q * 8] = h;
                *(shortx8*)&Bl2[s][col * 40 + q * 8] = l;
            }
        }
        shortx8 ah[2][2], al[2][2];
#pragma unroll
        for (int s = 0; s < 2; ++s) {
            int kb = kb2 * 2 + s;
            int k0 = kb * 32 + kq * 8;
#pragma unroll
            for (int rg = 0; rg < 2; ++rg) {
                int row = rowBase + rg * 16 + m;
                float4 p, q;
                if (kb < 4) {
                    p = elu4(*(const float4*)&A[(size_t)row * 128 + k0]);
                    q = elu4(*(const float4*)&A[(size_t)row * 128 + k0 + 4]);
                } else {
                    if (modeB == 0) {
                        // interleaved fp16: [(4*vert + (kb-4))*128 + b*32 + kq*8]
                        intx4 raw = *(const intx4*)&BsH[(size_t)(4 * vRow[rg] + (kb - 4)) * 128
                                                        + bRow[rg] * 32 + kq * 8];
                        float2 f0 = h2f(raw.x), f1 = h2f(raw.y);
                        float2 f2 = h2f(raw.z), f3 = h2f(raw.w);
                        p = elu4(make_float4(f0.x, f0.y, f1.x, f1.y));
                        q = elu4(make_float4(f2.x, f2.y, f3.x, f3.y));
                    } else {
                        int kk = k0 - 128;
                        p = *(const float4*)&Bsf[bRow[rg] * 128 + kk];
                        q = *(const float4*)&Bsf[bRow[rg] * 128 + kk + 4];
                    }
                }
                float x[8] = {p.x, p.y, p.z, p.w, q.x, q.y, q.z, q.w};
#pragma unroll
                for (int j = 0; j < 8; ++j) {
                    short h, l;
                    split2(x[j], h, l);
                    ah[s][rg][j] = h;
                    al[s][rg][j] = l;
                }
            }
        }
        __syncthreads();
#pragma unroll
        for (int ct = 0; ct < 8; ++ct) {
            int co = (ct * 16 + m) * 40 + kq * 8;
#pragma unroll
            for (int s = 0; s < 2; ++s) {
                shortx8 bh = *(const shortx8*)&Bh2[s][co];
                shortx8 bl = *(const shortx8*)&Bl2[s][co];
#pragma unroll
                for (int rg = 0; rg < 2; ++rg) {
                    acc[rg][ct] = __builtin_amdgcn_mfma_f32_16x16x32_bf16(ah[s][rg], bh, acc[rg][ct], 0, 0, 0);
                    acc[rg][ct] = __builtin_amdgcn_mfma_f32_16x16x32_bf16(ah[s][rg], bl, acc[rg][ct], 0, 0, 0);
                    acc[rg][ct] = __builtin_amdgcn_mfma_f32_16x16x32_bf16(al[s][rg], bh, acc[rg][ct], 0, 0, 0);
                }
            }
        }
    }
    // epilogue: C/D layout col=lane&15, row=(lane>>4)*4+reg  [verified m89/m91]
    const int bBlk = (blockIdx.x * 128) / rowsPerBatch;  // block spans <=2 batches
    float mk8[8]; int ib8[8];
    if (avgout) {
#pragma unroll
        for (int rg = 0; rg < 2; ++rg)
#pragma unroll
            for (int r = 0; r < 4; ++r) {
                int row = rowBase + rg * 16 + kq * 4 + r;
                mk8[rg * 4 + r] = mask[row];
                ib8[rg * 4 + r] = (row >= (bBlk + 1) * rowsPerBatch) ? 1 : 0;
            }
    }
    float cs1[8], cs2[8], av0[8], av1[8];
#pragma unroll
    for (int ct = 0; ct < 8; ++ct) { cs1[ct] = 0.f; cs2[ct] = 0.f; av0[ct] = 0.f; av1[ct] = 0.f; }
#pragma unroll
    for (int ct = 0; ct < 8; ++ct) {
        int col = ct * 16 + m;
        float bb = bp[col];
#pragma unroll
        for (int rg = 0; rg < 2; ++rg) {
#pragma unroll
            for (int r = 0; r < 4; ++r) {
                int row = rowBase + rg * 16 + kq * 4 + r;
                size_t o = (size_t)row * 128 + col;
                float v = acc[rg][ct][r] + bb;
                if (resid) v += resid[o];
                out[o] = v;
                if (shadow) {
                    int b = row / rowsPerBatch, vert = row - b * rowsPerBatch;
                    shadow[(size_t)(4 * vert + (col >> 5)) * 128 + b * 32 + (col & 31)] =
                        __float2half(v);
                }
                float e = eluf(v);
                cs1[ct] += e; cs2[ct] += e * e;
                if (avgout) {
                    float me = mk8[rg * 4 + r] * e;
                    if (ib8[rg * 4 + r]) av1[ct] += me; else av0[ct] += me;
                }
            }
        }
    }
    if (Sout) {  // fused stats (+ optional avg numerators) for the consuming layer
        __syncthreads();
        float* red = (float*)Bh2;
        float* redv = (float*)Bl2;
        red[t] = 0.f;
        if (avgout) redv[t] = 0.f;
        __syncthreads();
#pragma unroll
        for (int ct = 0; ct < 8; ++ct) {
            cs1[ct] += __shfl_xor(cs1[ct], 16); cs1[ct] += __shfl_xor(cs1[ct], 32);
            cs2[ct] += __shfl_xor(cs2[ct], 16); cs2[ct] += __shfl_xor(cs2[ct], 32);
            if (avgout) {
                av0[ct] += __shfl_xor(av0[ct], 16); av0[ct] += __shfl_xor(av0[ct], 32);
                av1[ct] += __shfl_xor(av1[ct], 16); av1[ct] += __shfl_xor(av1[ct], 32);
            }
        }
        if (kq == 0) {
#pragma unroll
            for (int ct = 0; ct < 8; ++ct) {
                atomicAdd(&red[ct * 16 + m], cs1[ct]);
                atomicAdd(&red[128 + ct * 16 + m], cs2[ct]);
                if (avgout) {
                    atomicAdd(&redv[ct * 16 + m], av0[ct]);
                    atomicAdd(&redv[128 + ct * 16 + m], av1[ct]);
                }
            }
        }
        __syncthreads();
        if (t < 128) atomicAdd(&Sout[t], red[t]);
        else atomicAdd(&Sout[256 + (t - 128)], red[t]);
        if (avgout) {
            int plane = t >> 7, col = t & 127;
            int b = bBlk + plane;
            if (b < 4) atomicAdd(&avgout[b * 128 + col], redv[t]);
        }
    }
}

__global__ void finalize_avg(const float* __restrict__ avgacc, const float* __restrict__ masksum,
                             float* __restrict__ avg, float* __restrict__ S, float fN) {
    int c = threadIdx.x;
    float s1 = 0.f, s2 = 0.f;
    for (int b = 0; b < 4; ++b) {
        float a = avgacc[b * 128 + c] / masksum[b];
        avg[b * 128 + c] = a;
        s1 += a; s2 += a * a;
    }
    S[128 + c] = s1 * fN;
    S[256 + 128 + c] = s2 * fN;
}

__global__ void fold_final(const float* __restrict__ S, const float* __restrict__ g2,
                           const float* __restrict__ be2, const float* __restrict__ W2,
                           const float* __restrict__ b2, float* __restrict__ W2p, float invR) {
    __shared__ float red[128];
    int c = threadIdx.x;
    float mean = S[c] * invR;
    float var = S[256 + c] * invR - mean * mean;
    float s = g2[c] / sqrtf(var + EPS);
    float w = W2[c];
    W2p[c] = s * w;
    red[c] = (be2[c] - mean * s) * w;
    __syncthreads();
    for (int st = 64; st > 0; st >>= 1) {
        if (c < st) red[c] += red[c + st];
        __syncthreads();
    }
    if (c == 0) W2p[128] = b2[0] + red[0];
}

__global__ void final_out_kernel(const float* __restrict__ f, const float* __restrict__ W2p,
                                 float* __restrict__ out) {
    int t = threadIdx.x;
    int w = t >> 6, lane = t & 63;
    int row = blockIdx.x * 4 + w;
    float a = eluf(f[(size_t)row * 128 + lane]) * W2p[lane] +
              eluf(f[(size_t)row * 128 + 64 + lane]) * W2p[64 + lane];
    for (int off = 32; off > 0; off >>= 1) a += __shfl_down(a, off);
    if (lane == 0) out[row] = a + W2p[128];
}

extern "C" void kernel_launch(void* const* d_in, const int* in_sizes, int n_in,
                              void* d_out, int out_size, void* d_ws, size_t ws_size,
                              hipStream_t stream) {
    const float* inputs = (const float*)d_in[0];
    const float* mask = (const float*)d_in[1];
    const int* Di_rows = (const int*)d_in[2];
    const int* Di_cols = (const int*)d_in[3];
    const float* Di_vals = (const float*)d_in[4];
    const int* DiA_rows = (const int*)d_in[5];
    const int* DiA_cols = (const int*)d_in[6];
    const float* DiA_vals = (const float*)d_in[7];
    const float* W1 = (const float*)d_in[8];
    const float* b1 = (const float*)d_in[9];
    const float* rn_gamma = (const float*)d_in[10];
    const float* rn_beta = (const float*)d_in[11];
    const float* rn_W = (const float*)d_in[12];
    const float* rn_b = (const float*)d_in[13];
    const float* g2 = (const float*)d_in[14];
    const float* be2 = (const float*)d_in[15];
    const float* W2 = (const float*)d_in[16];
    const float* b2 = (const float*)d_in[17];
    float* out = (float*)d_out;

    const int B = 4;
    const int BN = in_sizes[1];      // 48000
    const int N = BN / B;            // 12000
    const int BF = out_size;         // 96000
    const int Fn = BF / B;           // 24000
    const int nnz = in_sizes[2];     // 1,152,000
    const int RA = 4 * N;            // 48000
    const int RD = 4 * Fn;           // 96000

    float* ws = (float*)d_ws;
    size_t off = 0;
    float* vA = ws + off;  off += (size_t)BN * 128;
    float* fA = ws + off;  off += (size_t)BF * 128;
    float* xT = ws + off;  off += (size_t)BN * 128;               // avg-block scratch
    __half* msgH = (__half*)(ws + off); off += (size_t)BF * 128 / 2;  // fp16 spmm out, interleaved
    __half* vH = (__half*)(ws + off); off += (size_t)RA * 128 / 2;    // [r4][b][32] fp16
    __half* fH = (__half*)(ws + off); off += (size_t)RD * 128 / 2;
    int* ptrA    = (int*)(ws + off);  off += (size_t)RA + 4;
    int2* edgesA = (int2*)(ws + off); off += (size_t)nnz * 2;
    int* ptrD    = (int*)(ws + off);  off += (size_t)RD + 4;
    int2* edgesD = (int2*)(ws + off); off += (size_t)nnz * 2;
    int* tmpfill = (int*)(ws + off);  off += (size_t)RD;
    int* partials = (int*)(ws + off); off += 256;
    float* Sarena = ws + off; off += 33 * 512;   // pre-zeroed stats slots (2i+j map)
    float* Aarena = ws + off; off += 16 * 512;   // pre-zeroed avg-numerator slots
    float* msum = ws + off;   off += 4;
    float* avg = ws + off;    off += 512;
    short* Wh = (short*)(ws + off); off += 128 * 256 / 2;
    short* Wl = (short*)(ws + off); off += 128 * 256 / 2;
    float* bp = ws + off;  off += 128;
    float* W2p = ws + off; off += 132;

    const int eBlocks = nnz / 256;
    const int PA = (RA + 1023) / 1024;
    const int PD = (RD + 1023) / 1024;

    hipMemsetAsync(Sarena, 0, (33 * 512 + 16 * 512) * 4, stream);
    hipMemsetAsync(fA, 0, (size_t)BF * 128 * 4, stream);

    // ---- build CSR for DiA ----
    hipMemsetAsync(tmpfill, 0, (size_t)RA * 4, stream);
    hist_kernel<<<eBlocks, 256, 0, stream>>>(DiA_rows, tmpfill);
    partial_kernel<<<PA, 256, 0, stream>>>(tmpfill, partials, RA);
    scanp_kernel<<<1, 256, 0, stream>>>(partials, ptrA, PA, RA, nnz);
    apply_kernel<<<PA, 256, 0, stream>>>(tmpfill, partials, ptrA, RA);
    scatter_kernel<<<eBlocks, 256, 0, stream>>>(DiA_rows, DiA_cols, DiA_vals, tmpfill, edgesA);
    // ---- build CSR for Di ----
    hipMemsetAsync(tmpfill, 0, (size_t)RD * 4, stream);
    hist_kernel<<<eBlocks, 256, 0, stream>>>(Di_rows, tmpfill);
    partial_kernel<<<PD, 256, 0, stream>>>(tmpfill, partials, RD);
    scanp_kernel<<<1, 256, 0, stream>>>(partials, ptrD, PD, RD, nnz);
    apply_kernel<<<PD, 256, 0, stream>>>(tmpfill, partials, ptrD, RD);
    scatter_kernel<<<eBlocks, 256, 0, stream>>>(Di_rows, Di_cols, Di_vals, tmpfill, edgesD);

    // S slot map: conv layer (i,j) -> Sarena + 512*(2i+j); final conv -> slot 32.
    auto slot = [&](int i, int j) { return Sarena + 512 * (2 * i + j); };
    float* Sfinal = Sarena + 512 * 32;

    masksum_kernel<<<B, 256, 0, stream>>>(mask, msum, N);
    conv1_kernel<<<BN / 64, 256, 0, stream>>>(inputs, W1, b1, vA, vH, N, slot(0, 0));

    for (int i = 0; i < 15; ++i) {   // layer 15 (avg) is dead: output depends only on f
        if ((i & 1) == 0) {
            const float* g0 = rn_gamma + (size_t)(i * 2 + 0) * 256;
            const float* be0 = rn_beta + (size_t)(i * 2 + 0) * 256;
            const float* Wl0 = rn_W + (size_t)(i * 2 + 0) * 256 * 128;
            const float* bl0 = rn_b + (size_t)(i * 2 + 0) * 128;
            const float* g1 = rn_gamma + (size_t)(i * 2 + 1) * 256;
            const float* be1 = rn_beta + (size_t)(i * 2 + 1) * 256;
            const float* Wl1 = rn_W + (size_t)(i * 2 + 1) * 256 * 128;
            const float* bl1 = rn_b + (size_t)(i * 2 + 1) * 128;
            float* SoutV = (i < 14) ? slot(i + 1, 0) : nullptr;
            float* avgV = (i < 14) ? (Aarena + 512 * i) : nullptr;

            if (i == 0) {
                // f == 0 -> msg_v == 0 exactly: skip spmm; slot(0,0) B-half stays 0.
                fold_kernel<<<128, 256, 0, stream>>>(slot(0, 0), g0, be0, Wl0, bl0,
                                                     Wh, Wl, bp, 1.f / BN);
                gemm_mfma<<<BN / 128, 256, 0, stream>>>(vA, nullptr, nullptr, Wh, Wl, bp,
                                                        vA, vA, vH, SoutV, mask, avgV,
                                                        N, 2, 1);
            } else {
                spmm_csr_kernel<<<RA / 32, 1024, 0, stream>>>(ptrA, edgesA,
                                                              (const __half2*)fH, msgH,
                                                              slot(i, 0));
                fold_kernel<<<128, 256, 0, stream>>>(slot(i, 0), g0, be0, Wl0, bl0,
                                                     Wh, Wl, bp, 1.f / BN);
                gemm_mfma<<<BN / 128, 256, 0, stream>>>(vA, msgH, nullptr, Wh, Wl, bp,
                                                        vA, vA, vH, SoutV, mask, avgV,
                                                        N, 0, 1);
            }

            spmm_csr_kernel<<<RD / 32, 1024, 0, stream>>>(ptrD, edgesD, (const __half2*)vH,
                                                          msgH, slot(i, 1));
            fold_kernel<<<128, 256, 0, stream>>>(slot(i, 1), g1, be1, Wl1, bl1, Wh, Wl,
                                                 bp, 1.f / BF);
            gemm_mfma<<<BF / 128, 256, 0, stream>>>(fA, msgH, nullptr, Wh, Wl, bp, nullptr,
                                                    fA, fH,
                                                    (i < 14) ? slot(i + 2, 1) : Sfinal,
                                                    nullptr, nullptr, Fn, 0, 1);
        } else {
            for (int j = 0; j < 2; ++j) {
                const float* g = rn_gamma + (size_t)(i * 2 + j) * 256;
                const float* be = rn_beta + (size_t)(i * 2 + j) * 256;
                const float* Wlw = rn_W + (size_t)(i * 2 + j) * 256 * 128;
                const float* bl = rn_b + (size_t)(i * 2 + j) * 128;
                const float* src = (j == 0) ? vA : xT;
                float* dst = (j == 0) ? xT : vA;
                const float* resid = (j == 0) ? nullptr : vA;
                __half* shadow = (j == 0) ? nullptr : vH;
                float* Sout = (j == 0) ? slot(i, 1) : slot(i + 1, 0);
                float* avgO = (j == 0) ? (Aarena + 512 * i) : nullptr;

                float* avgacc = Aarena + 512 * (i - 1 + j);
                finalize_avg<<<1, 128, 0, stream>>>(avgacc, msum, avg, slot(i, j),
                                                    (float)N);
                fold_kernel<<<128, 256, 0, stream>>>(slot(i, j), g, be, Wlw, bl, Wh, Wl,
                                                     bp, 1.f / BN);
                gemm_mfma<<<BN / 128, 256, 0, stream>>>(src, nullptr, avg, Wh, Wl, bp,
                                                        resid, dst, shadow, Sout, mask,
                                                        avgO, N, 1, 0);
            }
        }
    }

    fold_final<<<1, 128, 0, stream>>>(Sfinal, g2, be2, W2, b2, W2p, 1.f / BF);
    final_out_kernel<<<BF / 4, 256, 0, stream>>>(fA, W2p, out);
}

// Round 14
// 4147.076 us; speedup vs baseline: 1.0338x; 1.0338x over previous
//
#include <hip/hip_runtime.h>
#include <hip/hip_fp16.h>
#include <math.h>

// DirModelToFace on MI355X — round 14:
//  * REVERT rounds 12/13 (fp16 msg experiments, net loss): spmm/gemm restored to
//    round-11 exact (fp32 msg [b][r4][32], BK=32 gemm, plain edge loads; 4.195ms).
//  * finalize_avg fused into fold_kernel (avg-mode: mean/var from Aarena/msum
//    inline, block 0 writes avg) — removes 14 dispatches.
//  * CSR builds for DiA/Di merged via blockIdx.y (one chain instead of two
//    serial chains; shared memset) — removes 6 dispatches, overlaps real work.
//  * ~0.6ms of the 4.2ms is small-dispatch + gap overhead; this attacks it.

#define EPS 1e-5f

typedef float floatx4 __attribute__((ext_vector_type(4)));
typedef short shortx8 __attribute__((ext_vector_type(8)));

__device__ __forceinline__ float eluf(float x) { return x > 0.f ? x : expm1f(x); }
__device__ __forceinline__ float4 elu4(float4 v) {
    v.x = eluf(v.x); v.y = eluf(v.y); v.z = eluf(v.z); v.w = eluf(v.w); return v;
}
__device__ __forceinline__ short f2bf(float x) {  // round-to-nearest-even bf16
    unsigned u = __builtin_bit_cast(unsigned, x);
    u = u + 0x7FFFu + ((u >> 16) & 1u);
    return (short)(u >> 16);
}
__device__ __forceinline__ float bf2f(short h) {
    unsigned u = ((unsigned)(unsigned short)h) << 16;
    return __builtin_bit_cast(float, u);
}
// truncation hi/lo split: rem = x-bf2f(hi) exact in fp32; total err <= 2^-16|x|
__device__ __forceinline__ void split2(float x, short& hi, short& lo) {
    unsigned u = __builtin_bit_cast(unsigned, x);
    hi = (short)(u >> 16);
    float r = x - bf2f(hi);
    lo = (short)(__builtin_bit_cast(unsigned, r) >> 16);
}

// v = inputs @ W1 + b1; fp16 shadow; fused elu-stats (A-half of dir0 slot0).
__global__ void conv1_kernel(const float* __restrict__ in, const float* __restrict__ W1,
                             const float* __restrict__ b1, float* __restrict__ v,
                             __half* __restrict__ vH, int N, float* __restrict__ Sout) {
    int t = threadIdx.x;
    int c = t & 127, half = t >> 7;
    int r0 = blockIdx.x * 64;
    float w0 = W1[c], w1 = W1[128 + c], w2 = W1[256 + c], bb = b1[c];
    float s1 = 0.f, s2 = 0.f;
    for (int k = 0; k < 32; ++k) {
        int r = r0 + half + 2 * k;
        float x0 = in[r * 3 + 0], x1 = in[r * 3 + 1], x2 = in[r * 3 + 2];
        float val = bb + x0 * w0 + x1 * w1 + x2 * w2;
        v[(size_t)r * 128 + c] = val;
        int b = r / N, vert = r - b * N;
        vH[(size_t)(4 * vert + (c >> 5)) * 128 + b * 32 + (c & 31)] = __float2half(val);
        float e = eluf(val);
        s1 += e; s2 += e * e;
    }
    atomicAdd(&Sout[c], s1);
    atomicAdd(&Sout[256 + c], s2);
}

// masksum[b] = sum_n mask[b][n]
__global__ void masksum_kernel(const float* __restrict__ mask, float* __restrict__ msum,
                               int N) {
    int b = blockIdx.x, t = threadIdx.x;
    float s = 0.f;
    for (int n = t; n < N; n += 256) s += mask[(size_t)b * N + n];
    for (int o = 32; o > 0; o >>= 1) s += __shfl_down(s, o);
    __shared__ float sh[4];
    if ((t & 63) == 0) sh[t >> 6] = s;
    __syncthreads();
    if (t == 0) msum[b] = sh[0] + sh[1] + sh[2] + sh[3];
}

// ---------------- CSR build (A and D merged via blockIdx.y) ----------------

__global__ void hist2_kernel(const int* __restrict__ rowsA, const int* __restrict__ rowsD,
                             int* __restrict__ cntA, int* __restrict__ cntD) {
    int e = blockIdx.x * 256 + threadIdx.x;
    if (blockIdx.y == 0) atomicAdd(&cntA[rowsA[e]], 1);
    else atomicAdd(&cntD[rowsD[e]], 1);
}

__global__ void partial2_kernel(const int* __restrict__ cntA, const int* __restrict__ cntD,
                                int* __restrict__ partA, int* __restrict__ partD,
                                int RA, int RD) {
    const int* counts = blockIdx.y ? cntD : cntA;
    int* partials = blockIdx.y ? partD : partA;
    int R = blockIdx.y ? RD : RA;
    int t = threadIdx.x;
    int base = blockIdx.x * 1024 + t * 4;
    int s = 0;
#pragma unroll
    for (int j = 0; j < 4; ++j) { int i = base + j; if (i < R) s += counts[i]; }
    __shared__ int sh[256];
    sh[t] = s; __syncthreads();
    for (int st = 128; st > 0; st >>= 1) {
        if (t < st) sh[t] += sh[t + st];
        __syncthreads();
    }
    if (t == 0) partials[blockIdx.x] = sh[0];
}

__global__ void scanp2_kernel(int* __restrict__ partA, int* __restrict__ partD,
                              int* __restrict__ ptrA, int* __restrict__ ptrD,
                              int PA, int PD, int RA, int RD, int total) {
    int* partials = blockIdx.y ? partD : partA;
    int* rowptr = blockIdx.y ? ptrD : ptrA;
    int P = blockIdx.y ? PD : PA;
    int R = blockIdx.y ? RD : RA;
    __shared__ int sh[256];
    int t = threadIdx.x;
    int v = (t < P) ? partials[t] : 0;
    sh[t] = v; __syncthreads();
    for (int st = 1; st < 256; st <<= 1) {
        int tmp = (t >= st) ? sh[t - st] : 0;
        __syncthreads();
        sh[t] += tmp;
        __syncthreads();
    }
    if (t < P) partials[t] = sh[t] - v;
    if (t == 0) rowptr[R] = total;
}

__global__ void apply2_kernel(int* __restrict__ cntA, int* __restrict__ cntD,
                              const int* __restrict__ partA, const int* __restrict__ partD,
                              int* __restrict__ ptrA, int* __restrict__ ptrD,
                              int RA, int RD) {
    int* counts = blockIdx.y ? cntD : cntA;
    const int* partials = blockIdx.y ? partD : partA;
    int* rowptr = blockIdx.y ? ptrD : ptrA;
    int R = blockIdx.y ? RD : RA;
    int t = threadIdx.x;
    int base = blockIdx.x * 1024 + t * 4;
    int c[4]; int s = 0;
#pragma unroll
    for (int j = 0; j < 4; ++j) { int i = base + j; c[j] = (i < R) ? counts[i] : 0; s += c[j]; }
    __shared__ int sh[256];
    sh[t] = s; __syncthreads();
    for (int st = 1; st < 256; st <<= 1) {
        int tmp = (t >= st) ? sh[t - st] : 0;
        __syncthreads();
        sh[t] += tmp;
        __syncthreads();
    }
    int off = partials[blockIdx.x] + sh[t] - s;
#pragma unroll
    for (int j = 0; j < 4; ++j) {
        int i = base + j;
        if (i < R) { rowptr[i] = off; counts[i] = off; }
        off += c[j];
    }
}

__global__ void scatter2_kernel(const int* __restrict__ rowsA, const int* __restrict__ colsA,
                                const float* __restrict__ valsA,
                                const int* __restrict__ rowsD, const int* __restrict__ colsD,
                                const float* __restrict__ valsD,
                                int* __restrict__ fillA, int* __restrict__ fillD,
                                int2* __restrict__ edgesA, int2* __restrict__ edgesD) {
    int e = blockIdx.x * 256 + threadIdx.x;
    if (blockIdx.y == 0) {
        int p = atomicAdd(&fillA[rowsA[e]], 1);
        edgesA[p] = make_int2(colsA[e], __float_as_int(valsA[e]));
    } else {
        int p = atomicAdd(&fillD[rowsD[e]], 1);
        edgesD[p] = make_int2(colsD[e], __float_as_int(valsD[e]));
    }
}

// ---- CSR spmm: 16 waves/block, 2 rows/wave, 1 dword gather/edge, fused B stats ----
__global__ __launch_bounds__(1024) void spmm_csr_kernel(
    const int* __restrict__ rowptr, const int2* __restrict__ edges,
    const __half2* __restrict__ xH, float* __restrict__ y, int R4,
    float* __restrict__ Sout) {
    int t = threadIdx.x;
    int waveId = blockIdx.x * 16 + (t >> 6);
    int lane = t & 63;
    int b = lane >> 4, cp = lane & 15;
    const __half2* xb = xH + b * 16 + cp;
    size_t rs = (size_t)R4 * 32;
    __shared__ float red[256];
    if (t < 256) red[t] = 0.f;
    __syncthreads();
#pragma unroll
    for (int rr = 0; rr < 2; ++rr) {
        int r = waveId * 2 + rr;
        int e0 = rowptr[r], e1 = rowptr[r + 1];
        float ax = 0.f, ay = 0.f;
        int e = e0;
        for (; e + 4 <= e1; e += 4) {
            int2 E0 = edges[e], E1 = edges[e + 1], E2 = edges[e + 2], E3 = edges[e + 3];
            __half2 g0 = xb[(size_t)E0.x * 64];
            __half2 g1 = xb[(size_t)E1.x * 64];
            __half2 g2 = xb[(size_t)E2.x * 64];
            __half2 g3 = xb[(size_t)E3.x * 64];
            float v0 = __int_as_float(E0.y), v1 = __int_as_float(E1.y);
            float v2 = __int_as_float(E2.y), v3 = __int_as_float(E3.y);
            float2 f0 = __half22float2(g0), f1 = __half22float2(g1);
            float2 f2 = __half22float2(g2), f3 = __half22float2(g3);
            ax += v0 * f0.x; ay += v0 * f0.y;
            ax += v1 * f1.x; ay += v1 * f1.y;
            ax += v2 * f2.x; ay += v2 * f2.y;
            ax += v3 * f3.x; ay += v3 * f3.y;
        }
        for (; e < e1; ++e) {
            int2 E = edges[e];
            __half2 g = xb[(size_t)E.x * 64];
            float v = __int_as_float(E.y);
            float2 f = __half22float2(g);
            ax += v * f.x; ay += v * f.y;
        }
        *(float2*)&y[(size_t)b * rs + (size_t)r * 32 + cp * 2] = make_float2(ax, ay);
        float ea = eluf(ax), eb = eluf(ay);
        float s1a = ea, s2a = ea * ea, s1b = eb, s2b = eb * eb;
        s1a += __shfl_xor(s1a, 16); s1a += __shfl_xor(s1a, 32);
        s2a += __shfl_xor(s2a, 16); s2a += __shfl_xor(s2a, 32);
        s1b += __shfl_xor(s1b, 16); s1b += __shfl_xor(s1b, 32);
        s2b += __shfl_xor(s2b, 16); s2b += __shfl_xor(s2b, 32);
        if (lane < 16) {
            int ch = (r & 3) * 32 + cp * 2;
            atomicAdd(&red[ch], s1a);
            atomicAdd(&red[ch + 1], s1b);
            atomicAdd(&red[128 + ch], s2a);
            atomicAdd(&red[128 + ch + 1], s2b);
        }
    }
    __syncthreads();
    if (t < 128) atomicAdd(&Sout[128 + t], red[t]);
    else if (t < 256) atomicAdd(&Sout[384 + (t - 128)], red[t]);
}

// Fold BN into weights; emit bf16 hi/lo split in [col][k] layout for MFMA B-frags.
// avgacc != null: avg-block mode — B-half (k>=128) mean/var from Aarena/msum inline
// (identical arithmetic to the old finalize_avg+fold chain); block 0 writes avgOut.
__global__ void fold_kernel(const float* __restrict__ S, const float* __restrict__ gamma,
                            const float* __restrict__ beta, const float* __restrict__ W,
                            const float* __restrict__ bvec, short* __restrict__ Wh,
                            short* __restrict__ Wl, float* __restrict__ bp, float invR,
                            const float* __restrict__ avgacc, const float* __restrict__ msum,
                            float* __restrict__ avgOut) {
    __shared__ float red[256];
    int o = blockIdx.x, k = threadIdx.x;
    float mean, var;
    if (avgacc != nullptr && k >= 128) {
        int c = k - 128;
        float a0 = avgacc[c] / msum[0];
        float a1 = avgacc[128 + c] / msum[1];
        float a2 = avgacc[256 + c] / msum[2];
        float a3 = avgacc[384 + c] / msum[3];
        mean = 0.25f * (a0 + a1 + a2 + a3);
        var = 0.25f * (a0 * a0 + a1 * a1 + a2 * a2 + a3 * a3) - mean * mean;
        if (o == 0) {
            avgOut[c] = a0; avgOut[128 + c] = a1;
            avgOut[256 + c] = a2; avgOut[384 + c] = a3;
        }
    } else {
        mean = S[k] * invR;
        var = S[256 + k] * invR - mean * mean;
    }
    float s = gamma[k] / sqrtf(var + EPS);
    float w = W[(size_t)k * 128 + o];
    float wp = s * w;
    short h = f2bf(wp);
    Wh[(size_t)o * 256 + k] = h;
    Wl[(size_t)o * 256 + k] = f2bf(wp - bf2f(h));
    red[k] = (beta[k] - mean * s) * w;
    __syncthreads();
    for (int st = 128; st > 0; st >>= 1) {
        if (k < st) red[k] += red[k + st];
        __syncthreads();
    }
    if (k == 0) bp[o] = bvec[o] + red[0];
}

// MFMA GEMM (bf16 hi/lo split, fp32 acc), BK=32 LDS staging, fused stats+avg epilogue.
// modeB: 0 = per-row fp32 B (msg), 1 = broadcast fp32 avg, 2 = B identically zero.
__global__ __launch_bounds__(256) void gemm_mfma(
    const float* __restrict__ A, const float* __restrict__ Bs,
    const short* __restrict__ Wh, const short* __restrict__ Wl,
    const float* __restrict__ bp, const float* __restrict__ resid,
    float* __restrict__ out, __half* __restrict__ shadow,
    float* __restrict__ Sout, const float* __restrict__ mask,
    float* __restrict__ avgout, int rowsPerBatch, int modeB, int eluB) {
    __shared__ short Bsh[128 * 40];
    __shared__ short Bsl[128 * 40];
    const int t = threadIdx.x;
    const int lane = t & 63;
    const int wave = t >> 6;
    const int rowBase = blockIdx.x * 128 + wave * 32;
    const int m = lane & 15;
    const int kq = lane >> 4;
    floatx4 acc[2][8];
#pragma unroll
    for (int i = 0; i < 2; ++i)
#pragma unroll
        for (int j = 0; j < 8; ++j) acc[i][j] = {0.f, 0.f, 0.f, 0.f};

    const int kbEnd = (modeB == 2) ? 4 : 8;
    for (int kb = 0; kb < kbEnd; ++kb) {
        const int k0 = kb * 32 + kq * 8;
        __syncthreads();
#pragma unroll
        for (int i = 0; i < 2; ++i) {
            int idx = t + 256 * i;
            int col = idx >> 2, q = idx & 3;
            shortx8 h = *(const shortx8*)&Wh[(size_t)col * 256 + kb * 32 + q * 8];
            shortx8 l = *(const shortx8*)&Wl[(size_t)col * 256 + kb * 32 + q * 8];
            *(shortx8*)&Bsh[col * 40 + q * 8] = h;
            *(shortx8*)&Bsl[col * 40 + q * 8] = l;
        }
        shortx8 ah[2], al[2];
#pragma unroll
        for (int rg = 0; rg < 2; ++rg) {
            int row = rowBase + rg * 16 + m;
            float4 p, q;
            if (kb < 4) {
                p = elu4(*(const float4*)&A[(size_t)row * 128 + k0]);
                q = elu4(*(const float4*)&A[(size_t)row * 128 + k0 + 4]);
            } else {
                int kk = k0 - 128;
                if (modeB == 0) {
                    p = *(const float4*)&Bs[(size_t)row * 128 + kk];
                    q = *(const float4*)&Bs[(size_t)row * 128 + kk + 4];
                    if (eluB) { p = elu4(p); q = elu4(q); }
                } else {
                    int b = row / rowsPerBatch;
                    p = *(const float4*)&Bs[b * 128 + kk];
                    q = *(const float4*)&Bs[b * 128 + kk + 4];
                }
            }
            float x[8] = {p.x, p.y, p.z, p.w, q.x, q.y, q.z, q.w};
#pragma unroll
            for (int j = 0; j < 8; ++j) {
                short h, l;
                split2(x[j], h, l);
                ah[rg][j] = h;
                al[rg][j] = l;
            }
        }
        __syncthreads();
#pragma unroll
        for (int ct = 0; ct < 8; ++ct) {
            int co = (ct * 16 + m) * 40 + kq * 8;
            shortx8 bh = *(const shortx8*)&Bsh[co];
            shortx8 bl = *(const shortx8*)&Bsl[co];
#pragma unroll
            for (int rg = 0; rg < 2; ++rg) {
                acc[rg][ct] = __builtin_amdgcn_mfma_f32_16x16x32_bf16(ah[rg], bh, acc[rg][ct], 0, 0, 0);
                acc[rg][ct] = __builtin_amdgcn_mfma_f32_16x16x32_bf16(ah[rg], bl, acc[rg][ct], 0, 0, 0);
                acc[rg][ct] = __builtin_amdgcn_mfma_f32_16x16x32_bf16(al[rg], bh, acc[rg][ct], 0, 0, 0);
            }
        }
    }
    // epilogue: C/D layout col=lane&15, row=(lane>>4)*4+reg  [verified m89/m91]
    const int bBlk = (blockIdx.x * 128) / rowsPerBatch;  // block spans <=2 batches
    float mk8[8]; int ib8[8];
    if (avgout) {
#pragma unroll
        for (int rg = 0; rg < 2; ++rg)
#pragma unroll
            for (int r = 0; r < 4; ++r) {
                int row = rowBase + rg * 16 + kq * 4 + r;
                mk8[rg * 4 + r] = mask[row];
                ib8[rg * 4 + r] = (row >= (bBlk + 1) * rowsPerBatch) ? 1 : 0;
            }
    }
    float cs1[8], cs2[8], av0[8], av1[8];
#pragma unroll
    for (int ct = 0; ct < 8; ++ct) { cs1[ct] = 0.f; cs2[ct] = 0.f; av0[ct] = 0.f; av1[ct] = 0.f; }
#pragma unroll
    for (int ct = 0; ct < 8; ++ct) {
        int col = ct * 16 + m;
        float bb = bp[col];
#pragma unroll
        for (int rg = 0; rg < 2; ++rg) {
#pragma unroll
            for (int r = 0; r < 4; ++r) {
                int row = rowBase + rg * 16 + kq * 4 + r;
                size_t o = (size_t)row * 128 + col;
                float v = acc[rg][ct][r] + bb;
                if (resid) v += resid[o];
                out[o] = v;
                if (shadow) {
                    int b = row / rowsPerBatch, vert = row - b * rowsPerBatch;
                    shadow[(size_t)(4 * vert + (col >> 5)) * 128 + b * 32 + (col & 31)] =
                        __float2half(v);
                }
                float e = eluf(v);
                cs1[ct] += e; cs2[ct] += e * e;
                if (avgout) {
                    float me = mk8[rg * 4 + r] * e;
                    if (ib8[rg * 4 + r]) av1[ct] += me; else av0[ct] += me;
                }
            }
        }
    }
    if (Sout) {  // fused stats (+ optional avg numerators) for the consuming layer
        __syncthreads();
        float* red = (float*)Bsh;
        float* redv = (float*)Bsl;
        red[t] = 0.f;
        if (avgout) redv[t] = 0.f;
        __syncthreads();
#pragma unroll
        for (int ct = 0; ct < 8; ++ct) {
            cs1[ct] += __shfl_xor(cs1[ct], 16); cs1[ct] += __shfl_xor(cs1[ct], 32);
            cs2[ct] += __shfl_xor(cs2[ct], 16); cs2[ct] += __shfl_xor(cs2[ct], 32);
            if (avgout) {
                av0[ct] += __shfl_xor(av0[ct], 16); av0[ct] += __shfl_xor(av0[ct], 32);
                av1[ct] += __shfl_xor(av1[ct], 16); av1[ct] += __shfl_xor(av1[ct], 32);
            }
        }
        if (kq == 0) {
#pragma unroll
            for (int ct = 0; ct < 8; ++ct) {
                atomicAdd(&red[ct * 16 + m], cs1[ct]);
                atomicAdd(&red[128 + ct * 16 + m], cs2[ct]);
                if (avgout) {
                    atomicAdd(&redv[ct * 16 + m], av0[ct]);
                    atomicAdd(&redv[128 + ct * 16 + m], av1[ct]);
                }
            }
        }
        __syncthreads();
        if (t < 128) atomicAdd(&Sout[t], red[t]);
        else atomicAdd(&Sout[256 + (t - 128)], red[t]);
        if (avgout) {
            int plane = t >> 7, col = t & 127;
            int b = bBlk + plane;
            if (b < 4) atomicAdd(&avgout[b * 128 + col], redv[t]);
        }
    }
}

__global__ void fold_final(const float* __restrict__ S, const float* __restrict__ g2,
                           const float* __restrict__ be2, const float* __restrict__ W2,
                           const float* __restrict__ b2, float* __restrict__ W2p, float invR) {
    __shared__ float red[128];
    int c = threadIdx.x;
    float mean = S[c] * invR;
    float var = S[256 + c] * invR - mean * mean;
    float s = g2[c] / sqrtf(var + EPS);
    float w = W2[c];
    W2p[c] = s * w;
    red[c] = (be2[c] - mean * s) * w;
    __syncthreads();
    for (int st = 64; st > 0; st >>= 1) {
        if (c < st) red[c] += red[c + st];
        __syncthreads();
    }
    if (c == 0) W2p[128] = b2[0] + red[0];
}

__global__ void final_out_kernel(const float* __restrict__ f, const float* __restrict__ W2p,
                                 float* __restrict__ out) {
    int t = threadIdx.x;
    int w = t >> 6, lane = t & 63;
    int row = blockIdx.x * 4 + w;
    float a = eluf(f[(size_t)row * 128 + lane]) * W2p[lane] +
              eluf(f[(size_t)row * 128 + 64 + lane]) * W2p[64 + lane];
    for (int off = 32; off > 0; off >>= 1) a += __shfl_down(a, off);
    if (lane == 0) out[row] = a + W2p[128];
}

extern "C" void kernel_launch(void* const* d_in, const int* in_sizes, int n_in,
                              void* d_out, int out_size, void* d_ws, size_t ws_size,
                              hipStream_t stream) {
    const float* inputs = (const float*)d_in[0];
    const float* mask = (const float*)d_in[1];
    const int* Di_rows = (const int*)d_in[2];
    const int* Di_cols = (const int*)d_in[3];
    const float* Di_vals = (const float*)d_in[4];
    const int* DiA_rows = (const int*)d_in[5];
    const int* DiA_cols = (const int*)d_in[6];
    const float* DiA_vals = (const float*)d_in[7];
    const float* W1 = (const float*)d_in[8];
    const float* b1 = (const float*)d_in[9];
    const float* rn_gamma = (const float*)d_in[10];
    const float* rn_beta = (const float*)d_in[11];
    const float* rn_W = (const float*)d_in[12];
    const float* rn_b = (const float*)d_in[13];
    const float* g2 = (const float*)d_in[14];
    const float* be2 = (const float*)d_in[15];
    const float* W2 = (const float*)d_in[16];
    const float* b2 = (const float*)d_in[17];
    float* out = (float*)d_out;

    const int B = 4;
    const int BN = in_sizes[1];      // 48000
    const int N = BN / B;            // 12000
    const int BF = out_size;         // 96000
    const int Fn = BF / B;           // 24000
    const int nnz = in_sizes[2];     // 1,152,000
    const int RA = 4 * N;            // 48000
    const int RD = 4 * Fn;           // 96000

    float* ws = (float*)d_ws;
    size_t off = 0;
    float* vA = ws + off;  off += (size_t)BN * 128;
    float* fA = ws + off;  off += (size_t)BF * 128;
    float* msg = ws + off; off += (size_t)BF * 128;   // fp32 spmm out; avg scratch
    __half* vH = (__half*)(ws + off); off += (size_t)RA * 128 / 2;  // [r4][b][32] fp16
    __half* fH = (__half*)(ws + off); off += (size_t)RD * 128 / 2;
    int* ptrA    = (int*)(ws + off);  off += (size_t)RA + 4;
    int2* edgesA = (int2*)(ws + off); off += (size_t)nnz * 2;
    int* ptrD    = (int*)(ws + off);  off += (size_t)RD + 4;
    int2* edgesD = (int2*)(ws + off); off += (size_t)nnz * 2;
    int* cntA    = (int*)(ws + off);  off += (size_t)RA;
    int* cntD    = (int*)(ws + off);  off += (size_t)RD;
    int* partA   = (int*)(ws + off);  off += 256;
    int* partD   = (int*)(ws + off);  off += 256;
    float* Sarena = ws + off; off += 33 * 512;   // pre-zeroed stats slots (2i+j map)
    float* Aarena = ws + off; off += 16 * 512;   // pre-zeroed avg-numerator slots
    float* msum = ws + off;   off += 4;
    float* avg = ws + off;    off += 512;
    short* Wh = (short*)(ws + off); off += 128 * 256 / 2;
    short* Wl = (short*)(ws + off); off += 128 * 256 / 2;
    float* bp = ws + off;  off += 128;
    float* W2p = ws + off; off += 132;

    const int eBlocks = nnz / 256;
    const int PA = (RA + 1023) / 1024;
    const int PD = (RD + 1023) / 1024;

    hipMemsetAsync(Sarena, 0, (33 * 512 + 16 * 512) * 4, stream);
    hipMemsetAsync(fA, 0, (size_t)BF * 128 * 4, stream);
    hipMemsetAsync(cntA, 0, (size_t)(RA + RD) * 4, stream);  // cntA+cntD contiguous

    // ---- build CSR for DiA and Di in one merged chain ----
    hist2_kernel<<<dim3(eBlocks, 2), 256, 0, stream>>>(DiA_rows, Di_rows, cntA, cntD);
    partial2_kernel<<<dim3(PD, 2), 256, 0, stream>>>(cntA, cntD, partA, partD, RA, RD);
    scanp2_kernel<<<dim3(1, 2), 256, 0, stream>>>(partA, partD, ptrA, ptrD, PA, PD,
                                                  RA, RD, nnz);
    apply2_kernel<<<dim3(PD, 2), 256, 0, stream>>>(cntA, cntD, partA, partD, ptrA, ptrD,
                                                   RA, RD);
    scatter2_kernel<<<dim3(eBlocks, 2), 256, 0, stream>>>(DiA_rows, DiA_cols, DiA_vals,
                                                          Di_rows, Di_cols, Di_vals,
                                                          cntA, cntD, edgesA, edgesD);

    // S slot map: conv layer (i,j) -> Sarena + 512*(2i+j); final conv -> slot 32.
    auto slot = [&](int i, int j) { return Sarena + 512 * (2 * i + j); };
    float* Sfinal = Sarena + 512 * 32;

    masksum_kernel<<<B, 256, 0, stream>>>(mask, msum, N);
    conv1_kernel<<<BN / 64, 256, 0, stream>>>(inputs, W1, b1, vA, vH, N, slot(0, 0));

    for (int i = 0; i < 15; ++i) {   // layer 15 (avg) is dead: output depends only on f
        if ((i & 1) == 0) {
            const float* g0 = rn_gamma + (size_t)(i * 2 + 0) * 256;
            const float* be0 = rn_beta + (size_t)(i * 2 + 0) * 256;
            const float* Wl0 = rn_W + (size_t)(i * 2 + 0) * 256 * 128;
            const float* bl0 = rn_b + (size_t)(i * 2 + 0) * 128;
            const float* g1 = rn_gamma + (size_t)(i * 2 + 1) * 256;
            const float* be1 = rn_beta + (size_t)(i * 2 + 1) * 256;
            const float* Wl1 = rn_W + (size_t)(i * 2 + 1) * 256 * 128;
            const float* bl1 = rn_b + (size_t)(i * 2 + 1) * 128;
            float* SoutV = (i < 14) ? slot(i + 1, 0) : nullptr;
            float* avgV = (i < 14) ? (Aarena + 512 * i) : nullptr;

            if (i == 0) {
                // f == 0 -> msg_v == 0 exactly: skip spmm; slot(0,0) B-half stays 0.
                fold_kernel<<<128, 256, 0, stream>>>(slot(0, 0), g0, be0, Wl0, bl0,
                                                     Wh, Wl, bp, 1.f / BN,
                                                     nullptr, nullptr, nullptr);
                gemm_mfma<<<BN / 128, 256, 0, stream>>>(vA, nullptr, Wh, Wl, bp, vA, vA,
                                                        vH, SoutV, mask, avgV, N, 2, 1);
            } else {
                spmm_csr_kernel<<<RA / 32, 1024, 0, stream>>>(ptrA, edgesA,
                                                              (const __half2*)fH, msg, RA,
                                                              slot(i, 0));
                fold_kernel<<<128, 256, 0, stream>>>(slot(i, 0), g0, be0, Wl0, bl0,
                                                     Wh, Wl, bp, 1.f / BN,
                                                     nullptr, nullptr, nullptr);
                gemm_mfma<<<BN / 128, 256, 0, stream>>>(vA, msg, Wh, Wl, bp, vA, vA,
                                                        vH, SoutV, mask, avgV, N, 0, 1);
            }

            spmm_csr_kernel<<<RD / 32, 1024, 0, stream>>>(ptrD, edgesD, (const __half2*)vH,
                                                          msg, RD, slot(i, 1));
            fold_kernel<<<128, 256, 0, stream>>>(slot(i, 1), g1, be1, Wl1, bl1, Wh, Wl,
                                                 bp, 1.f / BF, nullptr, nullptr, nullptr);
            gemm_mfma<<<BF / 128, 256, 0, stream>>>(fA, msg, Wh, Wl, bp, nullptr, fA, fH,
                                                    (i < 14) ? slot(i + 2, 1) : Sfinal,
                                                    nullptr, nullptr, Fn, 0, 1);
        } else {
            for (int j = 0; j < 2; ++j) {
                const float* g = rn_gamma + (size_t)(i * 2 + j) * 256;
                const float* be = rn_beta + (size_t)(i * 2 + j) * 256;
                const float* Wlw = rn_W + (size_t)(i * 2 + j) * 256 * 128;
                const float* bl = rn_b + (size_t)(i * 2 + j) * 128;
                const float* src = (j == 0) ? vA : msg;
                float* dst = (j == 0) ? msg : vA;
                const float* resid = (j == 0) ? nullptr : vA;
                __half* shadow = (j == 0) ? nullptr : vH;
                float* Sout = (j == 0) ? slot(i, 1) : slot(i + 1, 0);
                float* avgO = (j == 0) ? (Aarena + 512 * i) : nullptr;

                float* avgacc = Aarena + 512 * (i - 1 + j);
                // fold with fused finalize_avg (B-half stats from Aarena/msum inline)
                fold_kernel<<<128, 256, 0, stream>>>(slot(i, j), g, be, Wlw, bl, Wh, Wl,
                                                     bp, 1.f / BN, avgacc, msum, avg);
                gemm_mfma<<<BN / 128, 256, 0, stream>>>(src, avg, Wh, Wl, bp, resid, dst,
                                                        shadow, Sout, mask, avgO, N, 1, 0);
            }
        }
    }

    fold_final<<<1, 128, 0, stream>>>(Sfinal, g2, be2, W2, b2, W2p, 1.f / BF);
    final_out_kernel<<<BF / 4, 256, 0, stream>>>(fA, W2p, out);
}